// Round 5
// baseline (1665.018 us; speedup 1.0000x reference)
//
#include <hip/hip_runtime.h>
#include <hip/hip_bf16.h>

#define NBLK 50
#define HID  16
#define BATCH 16
#define HH 128
#define WW 128
#define PH 136
#define PW 136
#define NCH 2
#define PXS 32                 // shorts per pixel (64 B)
#define ROWE (PW*PXS)          // 4352 shorts = 8704 B per (row, chunk)
#define TAPE 512               // elements per A tap-fragment (64 lanes * 8)

typedef __attribute__((ext_vector_type(8))) short short8;
typedef __attribute__((ext_vector_type(4))) float floatx4;

static __device__ __forceinline__ unsigned short f2bf(float f) {
    unsigned int u = __float_as_uint(f);
    unsigned int r = (u + 0x7fffu + ((u >> 16) & 1u)) >> 16;
    return (unsigned short)r;
}

#define GLD16(gp, lp) __builtin_amdgcn_global_load_lds( \
    (__attribute__((address_space(1))) void*)(void*)(gp), \
    (__attribute__((address_space(3))) void*)(lp), 16, 0, 0)

// Stage one feats row-chunk (8704 B contiguous) into LDS.
static __device__ __forceinline__ void stage_row(const unsigned short* g, unsigned short* l, int tid) {
    const char* gb = (const char*)g;
    char* lb = (char*)l;
    GLD16(gb + tid * 16,        lb + (tid & ~63) * 16);
    GLD16(gb + 4096 + tid * 16, lb + 4096 + (tid & ~63) * 16);
    if (tid < 32) GLD16(gb + 8192 + tid * 16, lb + 8192 + (tid & ~63) * 16);
}

// Pack w1 (fp32 [50][16][51][9][9]) into A-fragment order:
// wbuf[blk][chunk][tap][lane][8], lane: m=lane&15 (hidden ch), k=(lane>>4)*8+j.
// Zero for c>blk (K-padding + write-channel read-safety).
__global__ void prep_w(const float* __restrict__ w1, unsigned short* __restrict__ wbuf) {
    int idx = blockIdx.x * 256 + threadIdx.x;
    const int total = NBLK * NCH * 81 * TAPE;
    if (idx >= total) return;
    int e    = idx & 7;
    int lane = (idx >> 3) & 63;
    int tap  = (idx >> 9) % 81;
    int bc   = idx / (81 * TAPE);
    int ch   = bc & 1, blk = bc >> 1;
    int hc   = lane & 15;
    int c    = ch * 32 + (lane >> 4) * 8 + e;
    float v = 0.f;
    if (c <= blk) v = w1[(((size_t)blk * HID + hc) * (1 + NBLK) + c) * 81 + tap];
    wbuf[idx] = f2bf(v);
}

// Zero only the halo pixels. Unwritten interior channels are safe: their
// weight columns are zeroed in wbuf, and 0xAA-poison bf16 is finite.
__global__ void zero_halo(unsigned short* __restrict__ feats) {
    int t = blockIdx.x * 256 + threadIdx.x;
    const int PPX = 2112;                 // halo px per (b, chunk)
    const int TOT = BATCH * NCH * PPX * 4;
    if (t >= TOT) return;
    int w    = t & 3;
    int rest = t >> 2;
    int p    = rest % PPX;
    int ch   = (rest / PPX) % NCH;
    int b    = rest / (PPX * NCH);
    int row, px;
    if (p < 1088) {                        // rows 0-3, 132-135 (full)
        int r4 = p / 136; px = p % 136;
        row = (r4 < 4) ? r4 : r4 + 128;
    } else {                               // rows 4-131, cols 0-3 & 132-135
        int q = p - 1088;
        row = 4 + (q >> 3);
        int c = q & 7;
        px = (c < 4) ? c : c + 128;
    }
    float4* dst = (float4*)((char*)feats +
        (((((size_t)b * PH + row) * NCH + ch) * ROWE + (size_t)px * PXS) * 2) + (size_t)w * 16);
    *dst = make_float4(0.f, 0.f, 0.f, 0.f);
}

// Scatter x into feats channel 0, chunk 0.
__global__ void init_x(const float* __restrict__ x, unsigned short* __restrict__ feats) {
    int idx = blockIdx.x * 256 + threadIdx.x;
    if (idx >= BATCH * HH * WW) return;
    int xw = idx & (WW - 1);
    int yy = (idx >> 7) & (HH - 1);
    int b  = idx >> 14;
    feats[(((size_t)b * PH + (yy + 4)) * NCH) * ROWE + (size_t)(xw + 4) * PXS] = f2bf(x[idx]);
}

// One pipeline step with COMPILE-TIME step index S: all Areg[(S-o)&3]
// indices fold to constants, so the 4-deep ky register window is SROA'd
// into real VGPRs (the rolled-loop version rematerialized A from global
// at every MFMA — round-4's VGPR_Count=112 proved the window never stuck).
template<int S>
static __device__ __forceinline__ void do_step(
    const unsigned short* fs, const unsigned short* wsrc,
    unsigned short (&sB)[2][ROWE], short8 (&Areg)[4][9], floatx4 (&acc)[4][2],
    int tid, int x0, int n, int kg)
{
    if (S < 11)
        stage_row(fs + (size_t)(S + 1) * NCH * ROWE, &sB[(S + 1) & 1][0], tid);

    const unsigned short* bb = &sB[S & 1][0];
    #pragma unroll
    for (int kx = 0; kx < 9; ++kx) {
        short8 B0 = *(const short8*)(bb + (x0 + kx + n) * PXS + kg * 8);
        short8 B1 = *(const short8*)(bb + (x0 + 16 + kx + n) * PXS + kg * 8);
        #pragma unroll
        for (int oo = 0; oo < 4; ++oo) {
            const int o = 3 - oo;   // descending: oldest A slot consumed first
            if (o <= S && S - o <= 8) {
                acc[o][0] = __builtin_amdgcn_mfma_f32_16x16x32_bf16(
                    Areg[(S - o) & 3][kx], B0, acc[o][0], 0, 0, 0);
                acc[o][1] = __builtin_amdgcn_mfma_f32_16x16x32_bf16(
                    Areg[(S - o) & 3][kx], B1, acc[o][1], 0, 0, 0);
            }
        }
    }
    if (S < 8) {
        #pragma unroll
        for (int kx = 0; kx < 9; ++kx)
            Areg[(S + 1) & 3][kx] =
                *(const short8*)(wsrc + (size_t)((S + 1) * 9 + kx) * TAPE);
    }
    __syncthreads();
}

// One dense block. wg = (b, 4-row strip), 4 waves x 32 px. Per step r the
// staged input row r serves all (o,ky) with o+ky==r: 4x B-frag reuse.
// A (weights) streams global->register window (L2-resident, coalesced).
__global__ __launch_bounds__(256, 2) void block_kern(
    unsigned short* feats, const unsigned short* __restrict__ wbuf,
    const float* __restrict__ b1, const float* __restrict__ w2,
    const float* __restrict__ b2, float* __restrict__ out,
    int blk, int nchunk)
{
    __shared__ __align__(16) unsigned short sB[2][ROWE];

    const int s    = blockIdx.x & 31;
    const int b    = blockIdx.x >> 5;
    const int tid  = threadIdx.x;
    const int lane = tid & 63;
    const int wv   = tid >> 6;
    const int n    = lane & 15;
    const int kg   = lane >> 4;
    const int x0   = wv * 32;

    floatx4 acc[4][2];
    #pragma unroll
    for (int o = 0; o < 4; ++o)
        #pragma unroll
        for (int t = 0; t < 2; ++t)
            acc[o][t] = (floatx4){0.f, 0.f, 0.f, 0.f};

    const unsigned short* fb = feats + (size_t)b * PH * NCH * ROWE;

    for (int c = 0; c < nchunk; ++c) {
        const unsigned short* wsrc = wbuf + (size_t)(blk * NCH + c) * 81 * TAPE + lane * 8;
        const unsigned short* fs   = fb + (size_t)((4 * s) * NCH + c) * ROWE;

        short8 Areg[4][9];
        stage_row(fs, &sB[0][0], tid);
        #pragma unroll
        for (int kx = 0; kx < 9; ++kx)
            Areg[0][kx] = *(const short8*)(wsrc + (size_t)kx * TAPE);
        __syncthreads();

        do_step<0>(fs, wsrc, sB, Areg, acc, tid, x0, n, kg);
        do_step<1>(fs, wsrc, sB, Areg, acc, tid, x0, n, kg);
        do_step<2>(fs, wsrc, sB, Areg, acc, tid, x0, n, kg);
        do_step<3>(fs, wsrc, sB, Areg, acc, tid, x0, n, kg);
        do_step<4>(fs, wsrc, sB, Areg, acc, tid, x0, n, kg);
        do_step<5>(fs, wsrc, sB, Areg, acc, tid, x0, n, kg);
        do_step<6>(fs, wsrc, sB, Areg, acc, tid, x0, n, kg);
        do_step<7>(fs, wsrc, sB, Areg, acc, tid, x0, n, kg);
        do_step<8>(fs, wsrc, sB, Areg, acc, tid, x0, n, kg);
        do_step<9>(fs, wsrc, sB, Areg, acc, tid, x0, n, kg);
        do_step<10>(fs, wsrc, sB, Areg, acc, tid, x0, n, kg);
        do_step<11>(fs, wsrc, sB, Areg, acc, tid, x0, n, kg);
    }

    // Epilogue: relu(h+b1)·w2, reduce 16 hidden, sigmoid, write out + feats.
    float b1v[4], w2v[4];
    #pragma unroll
    for (int r = 0; r < 4; ++r) {
        b1v[r] = b1[blk * HID + kg * 4 + r];
        w2v[r] = w2[blk * HID + kg * 4 + r];
    }
    const float bb2 = b2[blk];
    const int cw = blk + 1, cchunk = cw >> 5, cidx = cw & 31;

    #pragma unroll
    for (int o = 0; o < 4; ++o) {
        const int yrow = 4 * s + o;
        #pragma unroll
        for (int t = 0; t < 2; ++t) {
            float p = 0.f;
            #pragma unroll
            for (int r = 0; r < 4; ++r)
                p += fmaxf(acc[o][t][r] + b1v[r], 0.f) * w2v[r];
            p += __shfl_xor(p, 16, 64);
            p += __shfl_xor(p, 32, 64);
            if (kg == 0) {
                float yv = 1.f / (1.f + __expf(-(p + bb2)));
                int px = x0 + 16 * t + n;
                out[(((size_t)b * NBLK + blk) * HH + yrow) * WW + px] = yv;
                feats[(((size_t)b * PH + (yrow + 4)) * NCH + cchunk) * ROWE
                      + (size_t)(px + 4) * PXS + cidx] = f2bf(yv);
            }
        }
    }
}

extern "C" void kernel_launch(void* const* d_in, const int* in_sizes, int n_in,
                              void* d_out, int out_size, void* d_ws, size_t ws_size,
                              hipStream_t stream) {
    const float* x  = (const float*)d_in[0];
    const float* w1 = (const float*)d_in[1];
    const float* b1 = (const float*)d_in[2];
    const float* w2 = (const float*)d_in[3];
    const float* b2 = (const float*)d_in[4];
    float* out = (float*)d_out;

    unsigned short* feats = (unsigned short*)d_ws;
    size_t feats_bytes = (size_t)BATCH * PH * NCH * ROWE * sizeof(unsigned short); // ~37.9 MB
    unsigned short* wbuf = (unsigned short*)((char*)d_ws + feats_bytes);           // ~8.3 MB

    const int htotal = BATCH * NCH * 2112 * 4;
    zero_halo<<<(htotal + 255) / 256, 256, 0, stream>>>(feats);
    init_x<<<(BATCH * HH * WW + 255) / 256, 256, 0, stream>>>(x, feats);
    const int wtotal = NBLK * NCH * 81 * TAPE;
    prep_w<<<(wtotal + 255) / 256, 256, 0, stream>>>(w1, wbuf);

    for (int blk = 0; blk < NBLK; ++blk) {
        int nchunk = (blk + 32) / 32;  // ceil((blk+1)/32)
        block_kern<<<BATCH * 32, 256, 0, stream>>>(feats, wbuf, b1, w2, b2, out, blk, nchunk);
    }
}